// Round 9
// baseline (70.870 us; speedup 1.0000x reference)
//
#include <hip/hip_runtime.h>
#include <cstdint>
#include <cstddef>

typedef unsigned long long u64;

// Problem constants (N,P,T,H,W) = (8,32,16,384,384)
constexpr int N_  = 8;
constexpr int P_  = 32;
constexpr int T_  = 16;
constexpr int HW  = 384 * 384;        // 147456 pixels per mask
constexpr int WORDS = HW / 64;        // 2304 u64 words per mask
constexpr int GPN = HW / 256;         // 576 256-pixel groups per image
constexpr int PG  = N_ * P_ * HW / 256;   // 147456 pred groups
constexpr int TG  = N_ * T_ * HW / 256;   //  73728 true groups
constexpr int TOTG = PG + TG;             // 221184 groups
constexpr int BATCH = 8;                  // groups per wave-iteration (8 KB in flight)
constexpr int PACK_BLOCKS = 1728;         // 6912 waves * 4 iters * 8 groups = TOTG

// ---------------------------------------------------------------------------
// Pack BOTH inputs into bits (pred then true, one buffer). Ballot layout:
// word[g*4+j] bit l = pixel (g*256 + 4l + j). Wave w owns groups
// [w*32, w*32+32) as 4 batches of 8.
// The 8 coalesced 1 KB loads are INLINE ASM: hipcc provably re-serializes
// buffered loads in this kernel shape (r4/r6/r7/r8: VGPR stayed 20), so we
// force issue order with volatile asm, insert our own s_waitcnt vmcnt(0)
// (the compiler treats asm defs as complete - it adds no waits for them),
// and pin the dependent ballots below the waitcnt with sched_barrier(0)
// (guide rule #18: "memory" clobber does not order register-only VALU ops).
// ---------------------------------------------------------------------------
__global__ __launch_bounds__(256, 2)
void pack_all(const float* __restrict__ gp, const float* __restrict__ gt,
              u64* __restrict__ pk) {
    const int lane = threadIdx.x & 63;
    const int wave = blockIdx.x * 4 + (threadIdx.x >> 6);

    #pragma unroll
    for (int it = 0; it < 4; ++it) {
        const int g0 = (wave * 4 + it) * BATCH;   // first group of this batch
        const float4* src = (g0 < PG)
            ? reinterpret_cast<const float4*>(gp) + (size_t)g0 * 64
            : reinterpret_cast<const float4*>(gt) + (size_t)(g0 - PG) * 64;
        const float4* s = src + lane;

        float4 v0, v1, v2, v3, v4, v5, v6, v7;
        asm volatile("global_load_dwordx4 %0, %1, off" : "=v"(v0) : "v"(s));
        asm volatile("global_load_dwordx4 %0, %1, off" : "=v"(v1) : "v"(s + 64));
        asm volatile("global_load_dwordx4 %0, %1, off" : "=v"(v2) : "v"(s + 128));
        asm volatile("global_load_dwordx4 %0, %1, off" : "=v"(v3) : "v"(s + 192));
        asm volatile("global_load_dwordx4 %0, %1, off" : "=v"(v4) : "v"(s + 256));
        asm volatile("global_load_dwordx4 %0, %1, off" : "=v"(v5) : "v"(s + 320));
        asm volatile("global_load_dwordx4 %0, %1, off" : "=v"(v6) : "v"(s + 384));
        asm volatile("global_load_dwordx4 %0, %1, off" : "=v"(v7) : "v"(s + 448));

        __builtin_amdgcn_sched_barrier(0);
        asm volatile("s_waitcnt vmcnt(0)" ::: "memory");
        __builtin_amdgcn_sched_barrier(0);

        u64 w[BATCH][4];
        {
            const float4 vv[BATCH] = {v0, v1, v2, v3, v4, v5, v6, v7};
            #pragma unroll
            for (int i = 0; i < BATCH; ++i) {
                w[i][0] = __ballot(vv[i].x != 0.0f);
                w[i][1] = __ballot(vv[i].y != 0.0f);
                w[i][2] = __ballot(vv[i].z != 0.0f);
                w[i][3] = __ballot(vv[i].w != 0.0f);
            }
        }

        if (lane == 0) {
            ulonglong2* dst = reinterpret_cast<ulonglong2*>(pk + (size_t)g0 * 4);
            #pragma unroll
            for (int i = 0; i < BATCH; ++i) {
                ulonglong2 lo, hi;
                lo.x = w[i][0]; lo.y = w[i][1];
                hi.x = w[i][2]; hi.y = w[i][3];
                dst[2 * i]     = lo;
                dst[2 * i + 1] = hi;
            }
        }
    }
}

// ---------------------------------------------------------------------------
// iou_max per (n,p), one 256-thread block each. Pred words in registers
// (a[9]); k-outer / t-inner gives 16 independent coalesced (512 B/instr)
// L2/L3-hot loads per step. All 33 partial sums (area_p, 16 inter,
// 16 area_t) live in registers until one batched shuffle reduction.
// ---------------------------------------------------------------------------
__global__ __launch_bounds__(256)
void ioumax_kernel(const u64* __restrict__ pp, const u64* __restrict__ pt,
                   float* __restrict__ ioumax) {
    __shared__ int   red[4][33];
    __shared__ int   tot[33];
    __shared__ float shiou[T_];

    const int np  = blockIdx.x;          // n*P + p
    const int n   = np >> 5;
    const int tid = threadIdx.x;
    const int lane = tid & 63;
    const int wv   = tid >> 6;

    const u64* pw = pp + (size_t)np * WORDS;
    const u64* tb = pt + (size_t)n * T_ * WORDS;   // image-n true base

    u64 a[9];
    #pragma unroll
    for (int k = 0; k < 9; ++k) a[k] = pw[tid + 256 * k];

    int ap = 0;
    int inter[T_] = {};
    int areat[T_] = {};
    for (int k = 0; k < 9; ++k) {
        u64 tw[T_];
        #pragma unroll
        for (int t = 0; t < T_; ++t) tw[t] = tb[(size_t)t * WORDS + tid + 256 * k];
        ap += __popcll(a[k]);
        #pragma unroll
        for (int t = 0; t < T_; ++t) {
            inter[t] += __popcll(a[k] & tw[t]);
            areat[t] += __popcll(tw[t]);
        }
    }

    int vals[33];
    vals[0] = ap;
    #pragma unroll
    for (int t = 0; t < T_; ++t) { vals[1 + t] = inter[t]; vals[1 + T_ + t] = areat[t]; }

    #pragma unroll
    for (int i = 0; i < 33; ++i) {
        int v = vals[i];
        v += __shfl_down(v, 32);
        v += __shfl_down(v, 16);
        v += __shfl_down(v, 8);
        v += __shfl_down(v, 4);
        v += __shfl_down(v, 2);
        v += __shfl_down(v, 1);
        if (lane == 0) red[wv][i] = v;
    }
    __syncthreads();
    if (tid < 33) tot[tid] = red[0][tid] + red[1][tid] + red[2][tid] + red[3][tid];
    __syncthreads();
    if (tid < T_) {
        float it = (float)tot[1 + tid];
        float u  = (float)tot[0] + (float)tot[1 + T_ + tid] - it;
        shiou[tid] = (u > 0.0f) ? it / u : 0.0f;
    }
    __syncthreads();
    if (tid == 0) {
        float best = 0.0f;
        #pragma unroll
        for (int t = 0; t < T_; ++t) best = fmaxf(best, shiou[t]);
        ioumax[np] = best;
    }
}

// ---------------------------------------------------------------------------
// Per-pixel score, ballot bit layout. One block = 4 pixel-groups (1024 px)
// of one image; packed-pred words staged to LDS with coalesced loads,
// consumed as wave-uniform broadcast reads. Lane l of wave wv -> pixels
// (gblk+wv)*256 + 4l + j = bit l of word (gblk+wv)*4 + j.
// ---------------------------------------------------------------------------
__global__ __launch_bounds__(256)
void score_kernel(const u64* __restrict__ pm,
                  const float* __restrict__ ioumax,
                  float* __restrict__ out) {
    __shared__ u64   wlds[P_][16];
    __shared__ float iou[P_];

    const int tid  = threadIdx.x;
    const int lane = tid & 63;
    const int wv   = tid >> 6;
    const int gblk = blockIdx.x * 4;
    const int n    = gblk / GPN;
    const int gl0  = gblk - n * GPN;

    {
        int p = tid >> 3, k = tid & 7;
        const u64* s = pm + (size_t)(n * P_ + p) * WORDS + (size_t)gl0 * 4 + 2 * k;
        *reinterpret_cast<ulonglong2*>(&wlds[p][2 * k]) =
            *reinterpret_cast<const ulonglong2*>(s);
    }
    if (tid < P_) iou[tid] = ioumax[n * P_ + tid];
    __syncthreads();

    float num0 = 0.f, num1 = 0.f, num2 = 0.f, num3 = 0.f;
    int   den0 = 0, den1 = 0, den2 = 0, den3 = 0;
    #pragma unroll
    for (int p = 0; p < P_; ++p) {
        float w8 = iou[p];
        u64 w0 = wlds[p][wv * 4 + 0];   // uniform addr per wave -> broadcast
        u64 w1 = wlds[p][wv * 4 + 1];
        u64 w2 = wlds[p][wv * 4 + 2];
        u64 w3 = wlds[p][wv * 4 + 3];
        unsigned b0 = (unsigned)(w0 >> lane) & 1u;
        unsigned b1 = (unsigned)(w1 >> lane) & 1u;
        unsigned b2 = (unsigned)(w2 >> lane) & 1u;
        unsigned b3 = (unsigned)(w3 >> lane) & 1u;
        num0 += b0 ? w8 : 0.0f;  den0 += b0;
        num1 += b1 ? w8 : 0.0f;  den1 += b1;
        num2 += b2 ? w8 : 0.0f;  den2 += b2;
        num3 += b3 ? w8 : 0.0f;  den3 += b3;
    }

    float4 o;
    o.x = den0 ? num0 / (float)den0 : 0.0f;
    o.y = den1 ? num1 / (float)den1 : 0.0f;
    o.z = den2 ? num2 / (float)den2 : 0.0f;
    o.w = den3 ? num3 / (float)den3 : 0.0f;
    reinterpret_cast<float4*>(out)[(size_t)(gblk + wv) * 64 + lane] = o;
}

extern "C" void kernel_launch(void* const* d_in, const int* in_sizes, int n_in,
                              void* d_out, int out_size, void* d_ws, size_t ws_size,
                              hipStream_t stream) {
    const float* gp = (const float*)d_in[0];   // (N,P,H,W)
    const float* gt = (const float*)d_in[1];   // (N,T,H,W)
    float* out = (float*)d_out;                // (N,H,W)

    char* ws = (char*)d_ws;
    u64* packed   = (u64*)ws;                  // pred (4.72 MB) then true (2.36 MB)
    u64* packed_p = packed;
    u64* packed_t = packed + (size_t)PG * 4;
    float* ioumax = (float*)(ws + (size_t)TOTG * 4 * 8);   // 1 KB

    // Every output buffer (packed, ioumax, out) is fully overwritten each
    // call -> deterministic, no memset needed.
    hipLaunchKernelGGL(pack_all, dim3(PACK_BLOCKS), dim3(256), 0, stream,
                       gp, gt, packed);
    hipLaunchKernelGGL(ioumax_kernel, dim3(N_ * P_), dim3(256), 0, stream,
                       packed_p, packed_t, ioumax);
    hipLaunchKernelGGL(score_kernel, dim3(N_ * GPN / 4), dim3(256), 0, stream,
                       packed_p, ioumax, out);
}

// Round 10
// 70.794 us; speedup vs baseline: 1.0011x; 1.0011x over previous
//
#include <hip/hip_runtime.h>
#include <cstdint>
#include <cstddef>

typedef unsigned long long u64;

// Problem constants (N,P,T,H,W) = (8,32,16,384,384)
constexpr int N_  = 8;
constexpr int P_  = 32;
constexpr int T_  = 16;
constexpr int HW  = 384 * 384;        // 147456 pixels per mask
constexpr int WORDS = HW / 64;        // 2304 u64 words per mask
constexpr int GPN = HW / 256;         // 576 256-pixel groups per image
constexpr int PG  = N_ * P_ * HW / 256;   // 147456 pred groups
constexpr int TG  = N_ * T_ * HW / 256;   //  73728 true groups
constexpr int TOTG = PG + TG;             // 221184 groups
constexpr int PACK_BLOCKS = 3456;         // 13824 waves * 16 groups = TOTG exactly

// ---------------------------------------------------------------------------
// Pack BOTH inputs into bits (pred then true, one buffer). Ballot layout:
// word[g*4+j] bit l = pixel (g*256 + 4l + j).
// r4/r6/r8/r9 proved hipcc serializes REGISTER-returning global loads in this
// kernel shape no matter what (VGPR stayed 20 even with inline-asm loads).
// So we bypass the register path: global_load_lds DMA (no dest register ->
// nothing to sink, queue depth controlled only by vmcnt). Per batch a wave
// issues 4 x 1KB DMA back-to-back (4 KB in flight/wave, 128 KB/CU at full
// occupancy), waits vmcnt(0), then reads back via ds_read_b128 + ballots.
// LDS dest is wave-uniform base + lane*16 (the HW rule) = exactly our
// contiguous layout. Same-wave DMA->ds_read needs only the vmcnt wait, no
// barrier (each wave touches only its own 4 KB).
// ---------------------------------------------------------------------------
__global__ __launch_bounds__(256)
void pack_all(const float* __restrict__ gp, const float* __restrict__ gt,
              u64* __restrict__ pk) {
    __shared__ __align__(16) float stage[4][4][256];   // [wave][group][pixel], 16 KB

    const int lane = threadIdx.x & 63;
    const int wv   = threadIdx.x >> 6;
    const int wave = blockIdx.x * 4 + wv;              // 0..13823

    #pragma unroll
    for (int b = 0; b < 4; ++b) {
        const int g0 = wave * 16 + b * 4;              // first group of batch
        // PG % 16 == 0, so a wave (16 groups) never straddles gp/gt.
        const float* src = (g0 < PG) ? gp + (size_t)g0 * 256
                                     : gt + (size_t)(g0 - PG) * 256;

        #pragma unroll
        for (int c = 0; c < 4; ++c) {
            __builtin_amdgcn_global_load_lds(
                (const __attribute__((address_space(1))) void*)(src + (size_t)c * 256 + lane * 4),
                (__attribute__((address_space(3))) void*)(&stage[wv][c][0]),
                16, 0, 0);
        }
        asm volatile("s_waitcnt vmcnt(0)" ::: "memory");

        #pragma unroll
        for (int c = 0; c < 4; ++c) {
            float4 v = *reinterpret_cast<const float4*>(&stage[wv][c][lane * 4]);
            u64 w0 = __ballot(v.x != 0.0f);
            u64 w1 = __ballot(v.y != 0.0f);
            u64 w2 = __ballot(v.z != 0.0f);
            u64 w3 = __ballot(v.w != 0.0f);
            if (lane == 0) {
                ulonglong2 lo, hi;
                lo.x = w0; lo.y = w1; hi.x = w2; hi.y = w3;
                ulonglong2* dst = reinterpret_cast<ulonglong2*>(pk + (size_t)(g0 + c) * 4);
                dst[0] = lo; dst[1] = hi;
            }
        }
    }
}

// ---------------------------------------------------------------------------
// iou_max per (n,p), one 256-thread block each. Pred words in registers
// (a[9]); k-outer / t-inner gives 16 independent coalesced (512 B/instr)
// L2/L3-hot loads per step. All 33 partial sums (area_p, 16 inter,
// 16 area_t) live in registers until one batched shuffle reduction.
// ---------------------------------------------------------------------------
__global__ __launch_bounds__(256)
void ioumax_kernel(const u64* __restrict__ pp, const u64* __restrict__ pt,
                   float* __restrict__ ioumax) {
    __shared__ int   red[4][33];
    __shared__ int   tot[33];
    __shared__ float shiou[T_];

    const int np  = blockIdx.x;          // n*P + p
    const int n   = np >> 5;
    const int tid = threadIdx.x;
    const int lane = tid & 63;
    const int wv   = tid >> 6;

    const u64* pw = pp + (size_t)np * WORDS;
    const u64* tb = pt + (size_t)n * T_ * WORDS;   // image-n true base

    u64 a[9];
    #pragma unroll
    for (int k = 0; k < 9; ++k) a[k] = pw[tid + 256 * k];

    int ap = 0;
    int inter[T_] = {};
    int areat[T_] = {};
    for (int k = 0; k < 9; ++k) {
        u64 tw[T_];
        #pragma unroll
        for (int t = 0; t < T_; ++t) tw[t] = tb[(size_t)t * WORDS + tid + 256 * k];
        ap += __popcll(a[k]);
        #pragma unroll
        for (int t = 0; t < T_; ++t) {
            inter[t] += __popcll(a[k] & tw[t]);
            areat[t] += __popcll(tw[t]);
        }
    }

    int vals[33];
    vals[0] = ap;
    #pragma unroll
    for (int t = 0; t < T_; ++t) { vals[1 + t] = inter[t]; vals[1 + T_ + t] = areat[t]; }

    #pragma unroll
    for (int i = 0; i < 33; ++i) {
        int v = vals[i];
        v += __shfl_down(v, 32);
        v += __shfl_down(v, 16);
        v += __shfl_down(v, 8);
        v += __shfl_down(v, 4);
        v += __shfl_down(v, 2);
        v += __shfl_down(v, 1);
        if (lane == 0) red[wv][i] = v;
    }
    __syncthreads();
    if (tid < 33) tot[tid] = red[0][tid] + red[1][tid] + red[2][tid] + red[3][tid];
    __syncthreads();
    if (tid < T_) {
        float it = (float)tot[1 + tid];
        float u  = (float)tot[0] + (float)tot[1 + T_ + tid] - it;
        shiou[tid] = (u > 0.0f) ? it / u : 0.0f;
    }
    __syncthreads();
    if (tid == 0) {
        float best = 0.0f;
        #pragma unroll
        for (int t = 0; t < T_; ++t) best = fmaxf(best, shiou[t]);
        ioumax[np] = best;
    }
}

// ---------------------------------------------------------------------------
// Per-pixel score, ballot bit layout. One block = 4 pixel-groups (1024 px)
// of one image; packed-pred words staged to LDS with coalesced loads,
// consumed as wave-uniform broadcast reads. Lane l of wave wv -> pixels
// (gblk+wv)*256 + 4l + j = bit l of word (gblk+wv)*4 + j.
// ---------------------------------------------------------------------------
__global__ __launch_bounds__(256)
void score_kernel(const u64* __restrict__ pm,
                  const float* __restrict__ ioumax,
                  float* __restrict__ out) {
    __shared__ u64   wlds[P_][16];
    __shared__ float iou[P_];

    const int tid  = threadIdx.x;
    const int lane = tid & 63;
    const int wv   = tid >> 6;
    const int gblk = blockIdx.x * 4;
    const int n    = gblk / GPN;
    const int gl0  = gblk - n * GPN;

    {
        int p = tid >> 3, k = tid & 7;
        const u64* s = pm + (size_t)(n * P_ + p) * WORDS + (size_t)gl0 * 4 + 2 * k;
        *reinterpret_cast<ulonglong2*>(&wlds[p][2 * k]) =
            *reinterpret_cast<const ulonglong2*>(s);
    }
    if (tid < P_) iou[tid] = ioumax[n * P_ + tid];
    __syncthreads();

    float num0 = 0.f, num1 = 0.f, num2 = 0.f, num3 = 0.f;
    int   den0 = 0, den1 = 0, den2 = 0, den3 = 0;
    #pragma unroll
    for (int p = 0; p < P_; ++p) {
        float w8 = iou[p];
        u64 w0 = wlds[p][wv * 4 + 0];   // uniform addr per wave -> broadcast
        u64 w1 = wlds[p][wv * 4 + 1];
        u64 w2 = wlds[p][wv * 4 + 2];
        u64 w3 = wlds[p][wv * 4 + 3];
        unsigned b0 = (unsigned)(w0 >> lane) & 1u;
        unsigned b1 = (unsigned)(w1 >> lane) & 1u;
        unsigned b2 = (unsigned)(w2 >> lane) & 1u;
        unsigned b3 = (unsigned)(w3 >> lane) & 1u;
        num0 += b0 ? w8 : 0.0f;  den0 += b0;
        num1 += b1 ? w8 : 0.0f;  den1 += b1;
        num2 += b2 ? w8 : 0.0f;  den2 += b2;
        num3 += b3 ? w8 : 0.0f;  den3 += b3;
    }

    float4 o;
    o.x = den0 ? num0 / (float)den0 : 0.0f;
    o.y = den1 ? num1 / (float)den1 : 0.0f;
    o.z = den2 ? num2 / (float)den2 : 0.0f;
    o.w = den3 ? num3 / (float)den3 : 0.0f;
    reinterpret_cast<float4*>(out)[(size_t)(gblk + wv) * 64 + lane] = o;
}

extern "C" void kernel_launch(void* const* d_in, const int* in_sizes, int n_in,
                              void* d_out, int out_size, void* d_ws, size_t ws_size,
                              hipStream_t stream) {
    const float* gp = (const float*)d_in[0];   // (N,P,H,W)
    const float* gt = (const float*)d_in[1];   // (N,T,H,W)
    float* out = (float*)d_out;                // (N,H,W)

    char* ws = (char*)d_ws;
    u64* packed   = (u64*)ws;                  // pred (4.72 MB) then true (2.36 MB)
    u64* packed_p = packed;
    u64* packed_t = packed + (size_t)PG * 4;
    float* ioumax = (float*)(ws + (size_t)TOTG * 4 * 8);   // 1 KB

    // Every output buffer (packed, ioumax, out) is fully overwritten each
    // call -> deterministic, no memset needed.
    hipLaunchKernelGGL(pack_all, dim3(PACK_BLOCKS), dim3(256), 0, stream,
                       gp, gt, packed);
    hipLaunchKernelGGL(ioumax_kernel, dim3(N_ * P_), dim3(256), 0, stream,
                       packed_p, packed_t, ioumax);
    hipLaunchKernelGGL(score_kernel, dim3(N_ * GPN / 4), dim3(256), 0, stream,
                       packed_p, ioumax, out);
}

// Round 11
// 70.067 us; speedup vs baseline: 1.0115x; 1.0104x over previous
//
#include <hip/hip_runtime.h>
#include <cstdint>
#include <cstddef>

typedef unsigned long long u64;

// Problem constants (N,P,T,H,W) = (8,32,16,384,384)
constexpr int N_  = 8;
constexpr int P_  = 32;
constexpr int T_  = 16;
constexpr int HW  = 384 * 384;        // 147456 pixels per mask
constexpr int WORDS = HW / 64;        // 2304 u64 words per mask
constexpr int GPN = HW / 256;         // 576 256-pixel groups per image
constexpr int PG  = N_ * P_ * HW / 256;   // 147456 pred groups
constexpr int TG  = N_ * T_ * HW / 256;   //  73728 true groups
constexpr int TOTG = PG + TG;             // 221184 groups
constexpr int BATCH = 8;                  // groups per wave-iteration
constexpr int PACK_BLOCKS = 1728;         // 6912 waves * 4 iters * 8 groups = TOTG

// ---------------------------------------------------------------------------
// Pack BOTH inputs into bits (pred then true, one buffer). Ballot layout:
// word[g*4+j] bit l = pixel (g*256 + 4l + j). r8 form: best timed (70.73).
// r8/r9/r10 established this kernel is at the read-path ceiling (~4 TB/s
// effective): register-ILP, inline-asm, and LDS-DMA variants all time
// identically, cold or L3-warm. Keep the simplest.
// ---------------------------------------------------------------------------
__global__ __launch_bounds__(256, 2)
void pack_all(const float* __restrict__ gp, const float* __restrict__ gt,
              u64* __restrict__ pk) {
    const int lane = threadIdx.x & 63;
    const int wave = blockIdx.x * 4 + (threadIdx.x >> 6);

    #pragma unroll
    for (int it = 0; it < 4; ++it) {
        const int g0 = (wave * 4 + it) * BATCH;   // first group of this batch
        const float4* src = (g0 < PG)
            ? reinterpret_cast<const float4*>(gp) + (size_t)g0 * 64
            : reinterpret_cast<const float4*>(gt) + (size_t)(g0 - PG) * 64;

        float4 v[BATCH];
        #pragma unroll
        for (int i = 0; i < BATCH; ++i) v[i] = src[(size_t)i * 64 + lane];

        __builtin_amdgcn_sched_barrier(0);

        u64 w[BATCH][4];
        #pragma unroll
        for (int i = 0; i < BATCH; ++i) {
            w[i][0] = __ballot(v[i].x != 0.0f);
            w[i][1] = __ballot(v[i].y != 0.0f);
            w[i][2] = __ballot(v[i].z != 0.0f);
            w[i][3] = __ballot(v[i].w != 0.0f);
        }

        if (lane == 0) {
            ulonglong2* dst = reinterpret_cast<ulonglong2*>(pk + (size_t)g0 * 4);
            #pragma unroll
            for (int i = 0; i < BATCH; ++i) {
                ulonglong2 lo, hi;
                lo.x = w[i][0]; lo.y = w[i][1];
                hi.x = w[i][2]; hi.y = w[i][3];
                dst[2 * i]     = lo;
                dst[2 * i + 1] = hi;
            }
        }
    }
}

// ---------------------------------------------------------------------------
// iou_max per (n,p), one 256-thread block each, XCD-AFFINE: blocks dispatch
// round-robin blockIdx%8 -> XCD, so mapping n = blockIdx&7 puts all 32
// blocks of image n on ONE XCD. Its L2 then fetches that image's packed_t
// (295 KB) once, instead of 8 XCDs each fetching a copy (~19 MB -> ~2.4 MB
// of L3 traffic). Pure perf heuristic - correctness is mapping-independent
// (the n,p -> blockIdx bijection covers all 256 outputs).
// Pred words in registers (a[9]); k-outer / t-inner gives 16 independent
// coalesced loads per step; all 33 partial sums reduced in one batch.
// ---------------------------------------------------------------------------
__global__ __launch_bounds__(256)
void ioumax_kernel(const u64* __restrict__ pp, const u64* __restrict__ pt,
                   float* __restrict__ ioumax) {
    __shared__ int   red[4][33];
    __shared__ int   tot[33];
    __shared__ float shiou[T_];

    const int n   = blockIdx.x & 7;      // XCD-affine image id
    const int p   = blockIdx.x >> 3;
    const int np  = n * P_ + p;
    const int tid = threadIdx.x;
    const int lane = tid & 63;
    const int wv   = tid >> 6;

    const u64* pw = pp + (size_t)np * WORDS;
    const u64* tb = pt + (size_t)n * T_ * WORDS;   // image-n true base

    u64 a[9];
    #pragma unroll
    for (int k = 0; k < 9; ++k) a[k] = pw[tid + 256 * k];

    int ap = 0;
    int inter[T_] = {};
    int areat[T_] = {};
    for (int k = 0; k < 9; ++k) {
        u64 tw[T_];
        #pragma unroll
        for (int t = 0; t < T_; ++t) tw[t] = tb[(size_t)t * WORDS + tid + 256 * k];
        ap += __popcll(a[k]);
        #pragma unroll
        for (int t = 0; t < T_; ++t) {
            inter[t] += __popcll(a[k] & tw[t]);
            areat[t] += __popcll(tw[t]);
        }
    }

    int vals[33];
    vals[0] = ap;
    #pragma unroll
    for (int t = 0; t < T_; ++t) { vals[1 + t] = inter[t]; vals[1 + T_ + t] = areat[t]; }

    #pragma unroll
    for (int i = 0; i < 33; ++i) {
        int v = vals[i];
        v += __shfl_down(v, 32);
        v += __shfl_down(v, 16);
        v += __shfl_down(v, 8);
        v += __shfl_down(v, 4);
        v += __shfl_down(v, 2);
        v += __shfl_down(v, 1);
        if (lane == 0) red[wv][i] = v;
    }
    __syncthreads();
    if (tid < 33) tot[tid] = red[0][tid] + red[1][tid] + red[2][tid] + red[3][tid];
    __syncthreads();
    if (tid < T_) {
        float it = (float)tot[1 + tid];
        float u  = (float)tot[0] + (float)tot[1 + T_ + tid] - it;
        shiou[tid] = (u > 0.0f) ? it / u : 0.0f;
    }
    __syncthreads();
    if (tid == 0) {
        float best = 0.0f;
        #pragma unroll
        for (int t = 0; t < T_; ++t) best = fmaxf(best, shiou[t]);
        ioumax[np] = best;
    }
}

// ---------------------------------------------------------------------------
// Per-pixel score, ballot bit layout. One block = 4 pixel-groups (1024 px)
// of one image; packed-pred words staged to LDS with coalesced loads,
// consumed as wave-uniform broadcast reads. Blocks read disjoint packed_p
// slices, so no cross-XCD re-read exists here by construction.
// ---------------------------------------------------------------------------
__global__ __launch_bounds__(256)
void score_kernel(const u64* __restrict__ pm,
                  const float* __restrict__ ioumax,
                  float* __restrict__ out) {
    __shared__ u64   wlds[P_][16];
    __shared__ float iou[P_];

    const int tid  = threadIdx.x;
    const int lane = tid & 63;
    const int wv   = tid >> 6;
    const int gblk = blockIdx.x * 4;
    const int n    = gblk / GPN;
    const int gl0  = gblk - n * GPN;

    {
        int p = tid >> 3, k = tid & 7;
        const u64* s = pm + (size_t)(n * P_ + p) * WORDS + (size_t)gl0 * 4 + 2 * k;
        *reinterpret_cast<ulonglong2*>(&wlds[p][2 * k]) =
            *reinterpret_cast<const ulonglong2*>(s);
    }
    if (tid < P_) iou[tid] = ioumax[n * P_ + tid];
    __syncthreads();

    float num0 = 0.f, num1 = 0.f, num2 = 0.f, num3 = 0.f;
    int   den0 = 0, den1 = 0, den2 = 0, den3 = 0;
    #pragma unroll
    for (int p = 0; p < P_; ++p) {
        float w8 = iou[p];
        u64 w0 = wlds[p][wv * 4 + 0];   // uniform addr per wave -> broadcast
        u64 w1 = wlds[p][wv * 4 + 1];
        u64 w2 = wlds[p][wv * 4 + 2];
        u64 w3 = wlds[p][wv * 4 + 3];
        unsigned b0 = (unsigned)(w0 >> lane) & 1u;
        unsigned b1 = (unsigned)(w1 >> lane) & 1u;
        unsigned b2 = (unsigned)(w2 >> lane) & 1u;
        unsigned b3 = (unsigned)(w3 >> lane) & 1u;
        num0 += b0 ? w8 : 0.0f;  den0 += b0;
        num1 += b1 ? w8 : 0.0f;  den1 += b1;
        num2 += b2 ? w8 : 0.0f;  den2 += b2;
        num3 += b3 ? w8 : 0.0f;  den3 += b3;
    }

    float4 o;
    o.x = den0 ? num0 / (float)den0 : 0.0f;
    o.y = den1 ? num1 / (float)den1 : 0.0f;
    o.z = den2 ? num2 / (float)den2 : 0.0f;
    o.w = den3 ? num3 / (float)den3 : 0.0f;
    reinterpret_cast<float4*>(out)[(size_t)(gblk + wv) * 64 + lane] = o;
}

extern "C" void kernel_launch(void* const* d_in, const int* in_sizes, int n_in,
                              void* d_out, int out_size, void* d_ws, size_t ws_size,
                              hipStream_t stream) {
    const float* gp = (const float*)d_in[0];   // (N,P,H,W)
    const float* gt = (const float*)d_in[1];   // (N,T,H,W)
    float* out = (float*)d_out;                // (N,H,W)

    char* ws = (char*)d_ws;
    u64* packed   = (u64*)ws;                  // pred (4.72 MB) then true (2.36 MB)
    u64* packed_p = packed;
    u64* packed_t = packed + (size_t)PG * 4;
    float* ioumax = (float*)(ws + (size_t)TOTG * 4 * 8);   // 1 KB

    // Every output buffer (packed, ioumax, out) is fully overwritten each
    // call -> deterministic, no memset needed.
    hipLaunchKernelGGL(pack_all, dim3(PACK_BLOCKS), dim3(256), 0, stream,
                       gp, gt, packed);
    hipLaunchKernelGGL(ioumax_kernel, dim3(N_ * P_), dim3(256), 0, stream,
                       packed_p, packed_t, ioumax);
    hipLaunchKernelGGL(score_kernel, dim3(N_ * GPN / 4), dim3(256), 0, stream,
                       packed_p, ioumax, out);
}